// Round 1
// 136.534 us; speedup vs baseline: 1.0825x; 1.0825x over previous
//
#include <hip/hip_runtime.h>
#include <hip/hip_bf16.h>

#define NSTEP 50
#define S51 51
#define HID 128
#define MT 64                  // rows per tile
#define BPB 16                 // batch elems per block (block owns them -> no global atomics)
#define RPB (BPB * S51)        // 816 valid rows per block
#define NTILE 13               // ceil(816/64): 832 rows, 16 masked (1.9% waste)
#define GRID (16384 / BPB)     // 1024 blocks
#define BLOCK 256              // 4 waves; wave mi owns hidden slice [mi*32, mi*32+32)

typedef __attribute__((ext_vector_type(4))) float floatx4;
typedef __attribute__((ext_vector_type(16))) float floatx16;
typedef __attribute__((ext_vector_type(8))) __bf16 bf16x8;

// 4 x f32 -> 4 packed fp8 e4m3 bytes (v_cvt_pk_fp8_f32, gfx950 OCP e4m3fn)
__device__ __forceinline__ unsigned pk4_fp8(float v0, float v1, float v2, float v3) {
    unsigned r = (unsigned)__builtin_amdgcn_cvt_pk_fp8_f32(v0, v1, 0, false);   // bytes 0,1
    r = (unsigned)__builtin_amdgcn_cvt_pk_fp8_f32(v2, v3, (int)r, true);        // bytes 2,3
    return r;
}

// Swizzled fp8 activation layout: row-major 64x128 bytes, rows = 16 chunks of 8B,
// phys_chunk = chunk ^ (row & 15). 8B-aligned for ds_read/write_b64.
__device__ __forceinline__ int sw8(int row, int chunk) {
    return row * HID + ((chunk ^ (row & 15)) << 3);   // in bytes
}

// Register-only C-operand build (address-taken aggregates spill — R7 lesson)
__device__ __forceinline__ floatx16 ld_bias16(const float* bs, int base) {
    const floatx4 t0 = *(const floatx4*)(&bs[base]);
    const floatx4 t1 = *(const floatx4*)(&bs[base + 8]);
    const floatx4 t2 = *(const floatx4*)(&bs[base + 16]);
    const floatx4 t3 = *(const floatx4*)(&bs[base + 24]);
    floatx16 v = {t0[0], t0[1], t0[2], t0[3], t1[0], t1[1], t1[2], t1[3],
                  t2[0], t2[1], t2[2], t2[3], t3[0], t3[1], t3[2], t3[3]};
    return v;
}

// R15: L1 moved off the VALU onto the matrix pipe. One bf16 32x32x16 MFMA per
// 32x32 output block (K=16 holds k=0:X-weight, k=1:h-weight; bias via C).
// D-layout of 32x32 MFMA is dtype-independent, so the relu->pk4_fp8->sw8 store
// is identical to the proven A2 epilogue. ts[51]=0 pads masked rows.
__device__ __forceinline__ void l1_tile(unsigned char* dst, int t,
                                        const float* tsp, const float* b1s,
                                        bf16x8 aw, float xv, __bf16 hb, float hm,
                                        int l31, int hi, int mi) {
    const int s1 = 4 * t + (l31 >> 4);       // ss for row l31; row l31+32 is +2
    bf16x8 bx0 = {}, bx1 = {};
    bx0[0] = (__bf16)(xv * tsp[s1] * hm);     bx0[1] = hb;
    bx1[0] = (__bf16)(xv * tsp[s1 + 2] * hm); bx1[1] = hb;
    const floatx16 ci = ld_bias16(b1s, mi * 32 + 4 * hi);
    floatx16 d0 = __builtin_amdgcn_mfma_f32_32x32x16_bf16(aw, bx0, ci, 0, 0, 0);
    floatx16 d1 = __builtin_amdgcn_mfma_f32_32x32x16_bf16(aw, bx1, ci, 0, 0, 0);
#pragma unroll
    for (int g = 0; g < 4; ++g) {
        const int chI = mi * 4 + g;
        unsigned p0 = pk4_fp8(fmaxf(d0[4 * g + 0], 0.0f), fmaxf(d0[4 * g + 1], 0.0f),
                              fmaxf(d0[4 * g + 2], 0.0f), fmaxf(d0[4 * g + 3], 0.0f));
        *(unsigned*)(&dst[sw8(l31, chI) + 4 * hi]) = p0;
        unsigned p1 = pk4_fp8(fmaxf(d1[4 * g + 0], 0.0f), fmaxf(d1[4 * g + 1], 0.0f),
                              fmaxf(d1[4 * g + 2], 0.0f), fmaxf(d1[4 * g + 3], 0.0f));
        *(unsigned*)(&dst[sw8(l31 + 32, chI) + 4 * hi]) = p1;
    }
}

// R15 on top of R12 (93.5 us best): (a) L1 2->128 layer via bf16 MFMA (removes
// ~96 VALU ops/thread/tile — the biggest VALU block; MfmaUtil was 24% vs
// VALUBusy 43%); (b) row remap lr = ss*16+bbl so consume lane tid has fixed
// bbl = tid&15 -> register accumulator + shfl_xor instead of 64 same-address
// LDS atomics per tile; rowmap LDS deleted; (c) LDS 40448->~37.4KB to make the
// 4th block/CU resident (occupancy measured 38% ~= 3 blocks).
// Ledger: LDS-bytes (R9), occupancy (R10/R11), VALU packing (R13/R14) closed;
// packed-f32 is NOT double-rate on CDNA4 (157.3 TF spec == scalar FMA rate).
__launch_bounds__(BLOCK, 4)
__global__ void monotonic_fused(const float* __restrict__ x, const float* __restrict__ h,
                                const float* __restrict__ w1, const float* __restrict__ b1,
                                const float* __restrict__ w2, const float* __restrict__ b2,
                                const float* __restrict__ w3, const float* __restrict__ b3,
                                const float* __restrict__ w4, const float* __restrict__ b4,
                                float* __restrict__ out) {
    __shared__ __align__(16) unsigned char A1[2][MT * HID];  // a1 fp8, 2 x 8 KB
    __shared__ __align__(16) unsigned char A2[2][MT * HID];  // a2 fp8, 2 x 8 KB
    __shared__ float b1s[HID], b2s[HID], b3s[HID], w4s[HID];
    __shared__ float fs[S51], ts[52];                        // ts[51] = 0 pads masked rows
    __shared__ float xs[BPB], hs[BPB];
    __shared__ float posum[2][4][MT];                        // parity x mi x row

    const int tid = threadIdx.x;
    const int lane = tid & 63;
    const int mi = tid >> 6;      // wave 0..3 = hidden 32-slice
    const int l31 = lane & 31;
    const int hi = lane >> 5;

    // ---- stage small tensors ----
    if (tid < HID) {
        b1s[tid] = b1[tid]; b2s[tid] = b2[tid]; b3s[tid] = b3[tid]; w4s[tid] = w4[tid];
    }
    if (tid < BPB) {
        xs[tid] = x[blockIdx.x * BPB + tid];
        hs[tid] = h[blockIdx.x * BPB + tid];
    }
    if (tid < 52) {
        if (tid < S51) {
            // Faithful port of compute_cc_weights (verified R1-R14)
            const float PI50 = 0.06283185307179586f;  // pi/50
            float acc = 1.0f;
            for (int i = 2; i <= 50; i += 2) {
                int m = (i * tid) % 100;  // exact argument reduction
                acc += (2.0f / (1.0f - (float)(i * i))) * cosf((float)m * PI50);
            }
            float ccw = acc * 0.04f * ((tid == 0 || tid == NSTEP) ? 0.5f : 1.0f);
            fs[tid] = ccw * 0.5f;                               // folds the (x-x0)*0.5 factor
            ts[tid] = (cosf((float)tid * PI50) + 1.0f) * 0.5f;  // (steps+1)/2
        } else {
            ts[51] = 0.0f;   // tile 12 rows with ss==51 read this (masked at consume)
        }
    }
    const float b4v = b4[0];
    const float hm = (hi == 0) ? 1.0f : 0.0f;   // zero the k=8..15 half of bf16 frags

    // ---- gather W2^T / W3^T A-operand fp8 fragments (coalesced over l31) ----
    long w2f[8], w3f[8];
    {
        const int irow = mi * 32 + l31;
#pragma unroll
        for (int kc = 0; kc < 8; ++kc) {
            const int kb = kc * 16 + hi * 8;
            unsigned lo2 = pk4_fp8(w2[(kb + 0) * HID + irow], w2[(kb + 1) * HID + irow],
                                   w2[(kb + 2) * HID + irow], w2[(kb + 3) * HID + irow]);
            unsigned hi2 = pk4_fp8(w2[(kb + 4) * HID + irow], w2[(kb + 5) * HID + irow],
                                   w2[(kb + 6) * HID + irow], w2[(kb + 7) * HID + irow]);
            w2f[kc] = (long)(((unsigned long long)hi2 << 32) | lo2);
            unsigned lo3 = pk4_fp8(w3[(kb + 0) * HID + irow], w3[(kb + 1) * HID + irow],
                                   w3[(kb + 2) * HID + irow], w3[(kb + 3) * HID + irow]);
            unsigned hi3 = pk4_fp8(w3[(kb + 4) * HID + irow], w3[(kb + 5) * HID + irow],
                                   w3[(kb + 6) * HID + irow], w3[(kb + 7) * HID + irow]);
            w3f[kc] = (long)(((unsigned long long)hi3 << 32) | lo3);
        }
    }
    // ---- W1 bf16 A-frag (once): lane j=mi*32+l31; k=0 -> w1[0][j], k=1 -> w1[1][j] ----
    bf16x8 aw = {};
    {
        const int j = mi * 32 + l31;
        aw[0] = (__bf16)(w1[j] * hm);
        aw[1] = (__bf16)(w1[HID + j] * hm);
    }
    __syncthreads();

    // per-lane constants: row remap lr = ss*16 + bbl  =>  bbl = r&15 fixed per lane
    const float xv = xs[l31 & 15];
    const __bf16 hb = (__bf16)(hs[l31 & 15] * hm);
    float accq = 0.0f;            // wave-0 per-lane quadrature accumulator (bbl = tid&15)

    // ---- L1 for tile 0 -> A1[0] ----
    l1_tile(A1[0], 0, ts, b1s, aw, xv, hb, hm, l31, hi, mi);
    __syncthreads();

    for (int s = 0; s <= NTILE; ++s) {
        const int pa = s & 1, pb = pa ^ 1;
        floatx16 a0, a1, c0, c1;

        // ---- L2-MFMA on tile s (read A1[pa]); bias as C of peeled MFMA ----
        if (s < NTILE) {
            const floatx16 ci = ld_bias16(b2s, mi * 32 + 4 * hi);
            long f0 = *(const long*)(&A1[pa][sw8(l31, hi)]);
            long f1 = *(const long*)(&A1[pa][sw8(l31 + 32, hi)]);
            a0 = __builtin_amdgcn_mfma_f32_32x32x16_fp8_fp8(w2f[0], f0, ci, 0, 0, 0);
            a1 = __builtin_amdgcn_mfma_f32_32x32x16_fp8_fp8(w2f[0], f1, ci, 0, 0, 0);
#pragma unroll
            for (int kc = 1; kc < 8; ++kc) {
                f0 = *(const long*)(&A1[pa][sw8(l31, kc * 2 + hi)]);
                f1 = *(const long*)(&A1[pa][sw8(l31 + 32, kc * 2 + hi)]);
                a0 = __builtin_amdgcn_mfma_f32_32x32x16_fp8_fp8(w2f[kc], f0, a0, 0, 0, 0);
                a1 = __builtin_amdgcn_mfma_f32_32x32x16_fp8_fp8(w2f[kc], f1, a1, 0, 0, 0);
            }
        }
        // ---- L3-MFMA on tile s-1 (read A2[pb]) — independent chain, overlaps L2 ----
        if (s >= 1) {
            const floatx16 ci = ld_bias16(b3s, mi * 32 + 4 * hi);
            long g0 = *(const long*)(&A2[pb][sw8(l31, hi)]);
            long g1 = *(const long*)(&A2[pb][sw8(l31 + 32, hi)]);
            c0 = __builtin_amdgcn_mfma_f32_32x32x16_fp8_fp8(w3f[0], g0, ci, 0, 0, 0);
            c1 = __builtin_amdgcn_mfma_f32_32x32x16_fp8_fp8(w3f[0], g1, ci, 0, 0, 0);
#pragma unroll
            for (int kc = 1; kc < 8; ++kc) {
                g0 = *(const long*)(&A2[pb][sw8(l31, kc * 2 + hi)]);
                g1 = *(const long*)(&A2[pb][sw8(l31 + 32, kc * 2 + hi)]);
                c0 = __builtin_amdgcn_mfma_f32_32x32x16_fp8_fp8(w3f[kc], g0, c0, 0, 0, 0);
                c1 = __builtin_amdgcn_mfma_f32_32x32x16_fp8_fp8(w3f[kc], g1, c1, 0, 0, 0);
            }
        }
        // ---- consume tile s-2 partials into registers (no atomics: bbl == tid&15) ----
        if (s >= 2 && tid < MT) {
            int lr = (s - 2) * MT + tid;
            if (lr < RPB) {
                float u = posum[pa][0][tid] + posum[pa][1][tid] + posum[pa][2][tid]
                        + posum[pa][3][tid] + b4v;
                float dz = u > 0.0f ? u + 1.0f : __expf(u);  // elu(u)+1
                accq += dz * fs[lr >> 4];                    // ss = lr>>4
            }
        }
        // ---- epilogue: relu(a) -> A2[pa] fp8 ----
        if (s < NTILE) {
#pragma unroll
            for (int g = 0; g < 4; ++g) {
                const int chI = mi * 4 + g;
                unsigned p0 = pk4_fp8(fmaxf(a0[4 * g + 0], 0.0f), fmaxf(a0[4 * g + 1], 0.0f),
                                      fmaxf(a0[4 * g + 2], 0.0f), fmaxf(a0[4 * g + 3], 0.0f));
                *(unsigned*)(&A2[pa][sw8(l31, chI) + 4 * hi]) = p0;
                unsigned p1 = pk4_fp8(fmaxf(a1[4 * g + 0], 0.0f), fmaxf(a1[4 * g + 1], 0.0f),
                                      fmaxf(a1[4 * g + 2], 0.0f), fmaxf(a1[4 * g + 3], 0.0f));
                *(unsigned*)(&A2[pa][sw8(l31 + 32, chI) + 4 * hi]) = p1;
            }
        }
        // ---- fused L4 for tile s-1 -> posum[pb] (plain stores) ----
        if (s >= 1) {
            float p0 = 0.0f, p1 = 0.0f;
#pragma unroll
            for (int g = 0; g < 4; ++g) {
                const floatx4 w4v = *(const floatx4*)(&w4s[mi * 32 + 8 * g + 4 * hi]);
#pragma unroll
                for (int rr = 0; rr < 4; ++rr) {
                    p0 = fmaf(fmaxf(c0[4 * g + rr], 0.0f), w4v[rr], p0);
                    p1 = fmaf(fmaxf(c1[4 * g + rr], 0.0f), w4v[rr], p1);
                }
            }
            p0 += __shfl_xor(p0, 32);
            p1 += __shfl_xor(p1, 32);
            if (hi == 0) {
                posum[pb][mi][l31] = p0;
                posum[pb][mi][l31 + 32] = p1;
            }
        }
        // ---- L1-MFMA for tile s+1 -> A1[pb] (A1[pb] last read in phase s-1) ----
        if (s + 1 < NTILE) {
            l1_tile(A1[pb], s + 1, ts, b1s, aw, xv, hb, hm, l31, hi, mi);
        }
        __syncthreads();
    }

    // final consume: tile NTILE-1 partials, then cross-lane reduce (lanes l, l^16,
    // l^32, l^48 share bbl = l&15) and write out — no LDS atomics anywhere.
    if (tid < MT) {
        int lr = (NTILE - 1) * MT + tid;
        if (lr < RPB) {
            const int pf = (NTILE - 1) & 1;
            float u = posum[pf][0][tid] + posum[pf][1][tid] + posum[pf][2][tid]
                    + posum[pf][3][tid] + b4v;
            float dz = u > 0.0f ? u + 1.0f : __expf(u);
            accq += dz * fs[lr >> 4];
        }
        accq += __shfl_xor(accq, 16);
        accq += __shfl_xor(accq, 32);
        if (tid < BPB) out[blockIdx.x * BPB + tid] = hs[tid] + accq * xs[tid];
    }
}

extern "C" void kernel_launch(void* const* d_in, const int* in_sizes, int n_in,
                              void* d_out, int out_size, void* d_ws, size_t ws_size,
                              hipStream_t stream) {
    const float* x  = (const float*)d_in[0];
    const float* h  = (const float*)d_in[1];
    const float* w1 = (const float*)d_in[2];
    const float* b1 = (const float*)d_in[3];
    const float* w2 = (const float*)d_in[4];
    const float* b2 = (const float*)d_in[5];
    const float* w3 = (const float*)d_in[6];
    const float* b3 = (const float*)d_in[7];
    const float* w4 = (const float*)d_in[8];
    const float* b4 = (const float*)d_in[9];
    float* out = (float*)d_out;

    monotonic_fused<<<GRID, BLOCK, 0, stream>>>(x, h, w1, b1, w2, b2, w3, b3, w4, b4, out);
}